// Round 1
// baseline (626.460 us; speedup 1.0000x reference)
//
#include <hip/hip_runtime.h>
#include <hip/hip_bf16.h>

// SubtractionGaussian: out[b,h,i,j] = ||q_i||^2 + ||k_j||^2 - 2 q_i.k_j
// B=4 H=8 Lq=Lk=2048 D=64, fp32 in/out.
// Write-bound: 537 MB output. Compute via bf16 MFMA (16x16x32), norms fp32 from bf16 LDS.

#define BH 32
#define LQ 2048
#define LK 2048
#define DD 64
#define TM 128
#define TN 128
#define LDA 72   // ushorts per As row (64 + 8 pad) -> 144 B row stride
#define LDB 130  // ushorts per Bs row (128 + 2 pad) -> 260 B row stride

typedef __attribute__((ext_vector_type(8))) short short8;
typedef __attribute__((ext_vector_type(4))) float f32x4;

__device__ __forceinline__ unsigned short f2bf(float f) {
  unsigned u = __builtin_bit_cast(unsigned, f);
  u += 0x7fffu + ((u >> 16) & 1u);  // round-to-nearest-even
  return (unsigned short)(u >> 16);
}

__device__ __forceinline__ float bflo(unsigned w) {
  return __builtin_bit_cast(float, w << 16);
}
__device__ __forceinline__ float bfhi(unsigned w) {
  return __builtin_bit_cast(float, w & 0xffff0000u);
}

__global__ __launch_bounds__(256) void sg_kernel(const float* __restrict__ Q,
                                                 const float* __restrict__ K,
                                                 float* __restrict__ out) {
  __shared__ __align__(16) unsigned short As[TM * LDA];  // Q tile, [m][k] bf16
  __shared__ __align__(16) unsigned short Bs[DD * LDB];  // K tile, [k][n] bf16
  __shared__ float q2s[TM];
  __shared__ float k2s[TN];

  const int bh  = blockIdx.z;
  const int gm0 = blockIdx.y * TM;
  const int gn0 = blockIdx.x * TN;
  const int tid = threadIdx.x;

  // ---- stage A (Q tile): each thread does half a row (32 floats -> 32 bf16) ----
  {
    int row  = tid >> 1;
    int half = tid & 1;
    const float4* src = (const float4*)(Q + ((size_t)bh * LQ + gm0 + row) * DD + half * 32);
#pragma unroll
    for (int g = 0; g < 4; ++g) {
      float4 a = src[2 * g];
      float4 b = src[2 * g + 1];
      int4 pk;
      pk.x = (int)((unsigned)f2bf(a.x) | ((unsigned)f2bf(a.y) << 16));
      pk.y = (int)((unsigned)f2bf(a.z) | ((unsigned)f2bf(a.w) << 16));
      pk.z = (int)((unsigned)f2bf(b.x) | ((unsigned)f2bf(b.y) << 16));
      pk.w = (int)((unsigned)f2bf(b.z) | ((unsigned)f2bf(b.w) << 16));
      *(int4*)&As[row * LDA + half * 32 + g * 8] = pk;
    }
  }

  // ---- stage B (K tile): [k][n] natural layout, coalesced float4 loads ----
  {
    int jl = (tid & 31) * 4;
#pragma unroll
    for (int it = 0; it < 8; ++it) {
      int c = it * 8 + (tid >> 5);
      float4 v = *(const float4*)(K + ((size_t)bh * DD + c) * LK + gn0 + jl);
      unsigned lo = (unsigned)f2bf(v.x) | ((unsigned)f2bf(v.y) << 16);
      unsigned hi = (unsigned)f2bf(v.z) | ((unsigned)f2bf(v.w) << 16);
      *(unsigned*)&Bs[c * LDB + jl]     = lo;   // 4B aligned (jl even, LDB*2%4==0)
      *(unsigned*)&Bs[c * LDB + jl + 2] = hi;
    }
  }

  __syncthreads();

  // ---- per-tile norms from staged bf16 (error << threshold) ----
  if (tid < TM) {
    float s = 0.f;
#pragma unroll
    for (int ch = 0; ch < 8; ++ch) {
      int4 pk = *(const int4*)&As[tid * LDA + ch * 8];
      float v;
      v = bflo((unsigned)pk.x); s += v * v; v = bfhi((unsigned)pk.x); s += v * v;
      v = bflo((unsigned)pk.y); s += v * v; v = bfhi((unsigned)pk.y); s += v * v;
      v = bflo((unsigned)pk.z); s += v * v; v = bfhi((unsigned)pk.z); s += v * v;
      v = bflo((unsigned)pk.w); s += v * v; v = bfhi((unsigned)pk.w); s += v * v;
    }
    q2s[tid] = s;
  } else if (tid < 192) {
    int j0 = (tid - 128) * 2;
    float s0 = 0.f, s1 = 0.f;
#pragma unroll
    for (int c = 0; c < DD; ++c) {
      unsigned w = *(const unsigned*)&Bs[c * LDB + j0];
      float v0 = bflo(w), v1 = bfhi(w);
      s0 += v0 * v0;
      s1 += v1 * v1;
    }
    k2s[j0] = s0;
    k2s[j0 + 1] = s1;
  }

  __syncthreads();

  // ---- MFMA: each wave owns a 64x64 sub-tile (4x4 of 16x16) ----
  const int wave = tid >> 6;
  const int lane = tid & 63;
  const int wm   = (wave >> 1) * 64;
  const int wn   = (wave & 1) * 64;
  const int n15  = lane & 15;
  const int qd   = lane >> 4;

  f32x4 acc[4][4];
#pragma unroll
  for (int mi = 0; mi < 4; ++mi)
#pragma unroll
    for (int ni = 0; ni < 4; ++ni)
      acc[mi][ni] = (f32x4){0.f, 0.f, 0.f, 0.f};

#pragma unroll
  for (int kk = 0; kk < DD; kk += 32) {
    short8 a[4], b[4];
#pragma unroll
    for (int mi = 0; mi < 4; ++mi)
      a[mi] = *(const short8*)&As[(wm + mi * 16 + n15) * LDA + kk + qd * 8];
#pragma unroll
    for (int ni = 0; ni < 4; ++ni) {
      __align__(16) unsigned short tmp[8];
#pragma unroll
      for (int jj = 0; jj < 8; ++jj)
        tmp[jj] = Bs[(kk + qd * 8 + jj) * LDB + wn + ni * 16 + n15];
      b[ni] = *(short8*)tmp;
    }
#pragma unroll
    for (int mi = 0; mi < 4; ++mi)
#pragma unroll
      for (int ni = 0; ni < 4; ++ni)
        acc[mi][ni] = __builtin_amdgcn_mfma_f32_16x16x32_bf16(a[mi], b[ni], acc[mi][ni], 0, 0, 0);
  }

  // ---- epilogue: q2 + k2 - 2*qk, C/D map col=lane&15, row=quad*4+reg ----
  const size_t obase = ((size_t)bh * LQ + gm0) * (size_t)LK + gn0;
#pragma unroll
  for (int mi = 0; mi < 4; ++mi) {
#pragma unroll
    for (int ni = 0; ni < 4; ++ni) {
      float k2v = k2s[wn + ni * 16 + n15];
#pragma unroll
      for (int r = 0; r < 4; ++r) {
        int lrow = wm + mi * 16 + qd * 4 + r;
        float v = q2s[lrow] + k2v - 2.0f * acc[mi][ni][r];
        out[obase + (size_t)lrow * LK + (size_t)(wn + ni * 16 + n15)] = v;
      }
    }
  }
}

extern "C" void kernel_launch(void* const* d_in, const int* in_sizes, int n_in,
                              void* d_out, int out_size, void* d_ws, size_t ws_size,
                              hipStream_t stream) {
  const float* Q = (const float*)d_in[0];
  const float* K = (const float*)d_in[1];
  float* out = (float*)d_out;
  dim3 grid(LK / TN, LQ / TM, BH);
  sg_kernel<<<grid, 256, 0, stream>>>(Q, K, out);
}

// Round 2
// 562.173 us; speedup vs baseline: 1.1144x; 1.1144x over previous
//
#include <hip/hip_runtime.h>
#include <hip/hip_bf16.h>

// SubtractionGaussian: out[b,h,i,j] = ||q_i||^2 + ||k_j||^2 - 2 q_i.k_j
// B=4 H=8 Lq=Lk=2048 D=64, fp32 in/out. Output = 537 MB -> write-bound.
// bf16 MFMA 16x16x32; BOTH operands staged [row][k] in LDS (K transposed on
// stage) so every fragment is one aligned ds_read_b128 (no gather/spill).
// Epilogue stages fp32 result in LDS, streams out as coalesced float4.

#define BH 32
#define LQ 2048
#define LK 2048
#define DD 64
#define TM 128
#define TN 128
#define LDT 72    // ushorts per LDS tile row (64 + 8 pad) -> 144 B stride
#define SST 136   // floats per staging row (128 + 8 pad) -> 544 B stride (quad bank offset 8 -> 2-way, free)

typedef __attribute__((ext_vector_type(8))) short short8;
typedef __attribute__((ext_vector_type(4))) float f32x4;

__device__ __forceinline__ unsigned f2bf(float f) {
  unsigned u = __builtin_bit_cast(unsigned, f);
  u += 0x7fffu + ((u >> 16) & 1u);  // RNE
  return u >> 16;
}
__device__ __forceinline__ float bflo(unsigned w) { return __builtin_bit_cast(float, w << 16); }
__device__ __forceinline__ float bfhi(unsigned w) { return __builtin_bit_cast(float, w & 0xffff0000u); }

__global__ __launch_bounds__(256, 4) void sg_kernel(const float* __restrict__ Q,
                                                    const float* __restrict__ K,
                                                    float* __restrict__ out) {
  // As (Q tile [m][k]) | Bt (K tile transposed [n][k]); reused as fp32 epilogue staging
  __shared__ __align__(16) unsigned short smem[2 * TM * LDT];  // 36,864 B
  __shared__ float norms[256];  // [0..127]=||q_m||^2, [128..255]=||k_n||^2

  unsigned short* As = smem;
  unsigned short* Bt = smem + TM * LDT;

  const int bh  = blockIdx.z;
  const int gm0 = blockIdx.y * TM;
  const int gn0 = blockIdx.x * TN;
  const int tid = threadIdx.x;

  // ---- stage A: Q tile [m][k], 8-float chunks -> one b128 LDS write each ----
  {
    const float* qbase = Q + ((size_t)bh * LQ + gm0) * DD;
#pragma unroll
    for (int it = 0; it < 4; ++it) {
      int c = it * 256 + tid;  // 8-float chunk id, 0..1023 (128 rows x 8 chunks)
      const float4* p = (const float4*)(qbase + c * 8);
      float4 a = p[0];
      float4 b = p[1];
      int4 pk;
      pk.x = (int)(f2bf(a.x) | (f2bf(a.y) << 16));
      pk.y = (int)(f2bf(a.z) | (f2bf(a.w) << 16));
      pk.z = (int)(f2bf(b.x) | (f2bf(b.y) << 16));
      pk.w = (int)(f2bf(b.z) | (f2bf(b.w) << 16));
      *(int4*)&As[(c >> 3) * LDT + (c & 7) * 8] = pk;
    }
  }

  // ---- stage B transposed: Bt[n][k]. Coalesced scalar loads (4 rows of one
  // column), pack 4 bf16 -> ds_write_b64. One-time cost, off hot path. ----
  {
    int col = tid & 127;
    int c0b = (tid >> 7) * 32;  // threads 0-127 do k 0..31, 128-255 do k 32..63
    const float* kp = K + (size_t)bh * DD * LK + gn0 + col;
#pragma unroll
    for (int it = 0; it < 8; ++it) {
      int c0 = c0b + it * 4;
      float v0 = kp[(size_t)(c0 + 0) * LK];
      float v1 = kp[(size_t)(c0 + 1) * LK];
      float v2 = kp[(size_t)(c0 + 2) * LK];
      float v3 = kp[(size_t)(c0 + 3) * LK];
      uint2 w;
      w.x = f2bf(v0) | (f2bf(v1) << 16);
      w.y = f2bf(v2) | (f2bf(v3) << 16);
      *(uint2*)&Bt[col * LDT + c0] = w;  // byte addr 144*col + 2*c0, 8B aligned
    }
  }

  __syncthreads();

  // ---- norms from staged bf16: tid<128 -> q rows, tid>=128 -> k cols.
  // As|Bt are contiguous with identical stride: row base = tid*LDT. ----
  {
    float s = 0.f;
#pragma unroll
    for (int ch = 0; ch < 8; ++ch) {
      int4 pk = *(const int4*)&smem[tid * LDT + ch * 8];
      float v;
      v = bflo((unsigned)pk.x); s += v * v; v = bfhi((unsigned)pk.x); s += v * v;
      v = bflo((unsigned)pk.y); s += v * v; v = bfhi((unsigned)pk.y); s += v * v;
      v = bflo((unsigned)pk.z); s += v * v; v = bfhi((unsigned)pk.z); s += v * v;
      v = bflo((unsigned)pk.w); s += v * v; v = bfhi((unsigned)pk.w); s += v * v;
    }
    norms[tid] = s;
  }

  // ---- MFMA: wave owns 64x64 (4x4 of 16x16x32), both frags are b128 reads ----
  const int wave = tid >> 6;
  const int lane = tid & 63;
  const int wm   = (wave >> 1) * 64;
  const int wn   = (wave & 1) * 64;
  const int n15  = lane & 15;
  const int qd   = lane >> 4;

  f32x4 acc[4][4];
#pragma unroll
  for (int mi = 0; mi < 4; ++mi)
#pragma unroll
    for (int ni = 0; ni < 4; ++ni)
      acc[mi][ni] = (f32x4){0.f, 0.f, 0.f, 0.f};

#pragma unroll
  for (int kk = 0; kk < DD; kk += 32) {
    short8 a[4], b[4];
#pragma unroll
    for (int mi = 0; mi < 4; ++mi)
      a[mi] = *(const short8*)&As[(wm + mi * 16 + n15) * LDT + kk + qd * 8];
#pragma unroll
    for (int ni = 0; ni < 4; ++ni)
      b[ni] = *(const short8*)&Bt[(wn + ni * 16 + n15) * LDT + kk + qd * 8];
#pragma unroll
    for (int mi = 0; mi < 4; ++mi)
#pragma unroll
      for (int ni = 0; ni < 4; ++ni)
        acc[mi][ni] = __builtin_amdgcn_mfma_f32_16x16x32_bf16(a[mi], b[ni], acc[mi][ni], 0, 0, 0);
  }

  // ---- epilogue: stage fp32 half-tiles (64x128) in LDS, stream float4 out.
  // C/D map: col=lane&15, row=quad*4+reg. ----
  float* sf = (float*)smem;
  const size_t obase = ((size_t)bh * LQ + gm0) * (size_t)LK + gn0;

  for (int h = 0; h < 2; ++h) {
    __syncthreads();  // h=0: tile reads done; h=1: previous copy reads done
    if ((wave >> 1) == h) {
#pragma unroll
      for (int mi = 0; mi < 4; ++mi) {
#pragma unroll
        for (int ni = 0; ni < 4; ++ni) {
          float k2v = norms[128 + wn + ni * 16 + n15];
#pragma unroll
          for (int r = 0; r < 4; ++r) {
            int lr = mi * 16 + qd * 4 + r;  // local row in half-tile
            sf[lr * SST + wn + ni * 16 + n15] =
                norms[h * 64 + lr] + k2v - 2.0f * acc[mi][ni][r];
          }
        }
      }
    }
    __syncthreads();
    int rr = tid >> 5;          // 0..7
    int cc = (tid & 31) * 4;    // 0..124
#pragma unroll
    for (int it = 0; it < 8; ++it) {
      int row = it * 8 + rr;
      float4 v = *(const float4*)&sf[row * SST + cc];
      *(float4*)&out[obase + (size_t)(h * 64 + row) * LK + cc] = v;
    }
  }
}

extern "C" void kernel_launch(void* const* d_in, const int* in_sizes, int n_in,
                              void* d_out, int out_size, void* d_ws, size_t ws_size,
                              hipStream_t stream) {
  const float* Q = (const float*)d_in[0];
  const float* K = (const float*)d_in[1];
  float* out = (float*)d_out;
  dim3 grid(LK / TN, LQ / TM, BH);
  sg_kernel<<<grid, 256, 0, stream>>>(Q, K, out);
}